// Round 2
// baseline (552.629 us; speedup 1.0000x reference)
//
#include <hip/hip_runtime.h>

// NeuralHashVoxel: multi-level hash-grid trilinear interpolation.
// N=1M points, L=6 levels, F=8 feats, T=524288 table rows, B=2^22 buckets.

static constexpr int      NPTS  = 1048576;
static constexpr int      LVLS  = 6;
static constexpr int      NF    = 8;
static constexpr int      TTAB  = 524288;
static constexpr unsigned BTAB  = 4194304u;          // 2^22 buckets per level
static constexpr unsigned BMASK = BTAB - 1u;         // mod B == & BMASK (B is pow2)
static constexpr unsigned P0 = 73856093u, P1 = 19349669u, P2 = 83492791u;

__global__ __launch_bounds__(256) void nhv_kernel(
    const float* __restrict__ qp,     // [N,3]
    const float* __restrict__ feat,   // [L,T,F]
    const int*   __restrict__ fidx,   // [L,B]  (-1 = empty)
    float*       __restrict__ out)    // [N,F]
{
    const int n = blockIdx.x * 256 + threadIdx.x;
    if (n >= NPTS) return;

    const float qx = qp[3 * n + 0];
    const float qy = qp[3 * n + 1];
    const float qz = qp[3 * n + 2];

    float acc[NF];
#pragma unroll
    for (int f = 0; f < NF; ++f) acc[f] = 0.0f;

    // 1/res at level 0 is 4.0; halves each level. All exact powers of two,
    // so q*inv == q/res bit-exactly.
    float inv = 4.0f;
    for (int i = 0; i < LVLS; ++i, inv *= 0.5f) {
        const float sx = qx * inv, sy = qy * inv, sz = qz * inv;
        const float bx = floorf(sx), by = floorf(sy), bz = floorf(sz);
        // base >= 0 always (queries in [0,50)), so uint32 wrap + mask == mod B
        const unsigned cx = (unsigned)(int)bx;
        const unsigned cy = (unsigned)(int)by;
        const unsigned cz = (unsigned)(int)bz;
        const unsigned h = cx * P0 + cy * P1 + cz * P2;

        const int* __restrict__ tab = fidx + (size_t)i * BTAB;

        int id[8];
#pragma unroll
        for (int k = 0; k < 8; ++k) {
            unsigned key = h;
            if (k & 4) key += P0;
            if (k & 2) key += P1;
            if (k & 1) key += P2;
            id[k] = tab[key & BMASK];
        }

        int mn = id[0];
#pragma unroll
        for (int k = 1; k < 8; ++k) mn = min(mn, id[k]);

        if (mn > -1) {  // all 8 corners valid -> gather features
            const float tx = sx - bx, ty = sy - by, tz = sz - bz;
            const float wxv[2] = {1.0f - tx, tx};
            const float wyv[2] = {1.0f - ty, ty};
            const float wzv[2] = {1.0f - tz, tz};
            const float* __restrict__ fb = feat + (size_t)i * (TTAB * NF);
#pragma unroll
            for (int k = 0; k < 8; ++k) {
                const float c = wxv[(k >> 2) & 1] * wyv[(k >> 1) & 1] * wzv[k & 1];
                const float4* p = (const float4*)(fb + (size_t)id[k] * NF);
                const float4 lo = p[0];
                const float4 hi = p[1];
                acc[0] += c * lo.x; acc[1] += c * lo.y;
                acc[2] += c * lo.z; acc[3] += c * lo.w;
                acc[4] += c * hi.x; acc[5] += c * hi.y;
                acc[6] += c * hi.z; acc[7] += c * hi.w;
            }
        }
    }

    float4* o = (float4*)(out + (size_t)n * NF);
    o[0] = make_float4(acc[0], acc[1], acc[2], acc[3]);
    o[1] = make_float4(acc[4], acc[5], acc[6], acc[7]);
}

extern "C" void kernel_launch(void* const* d_in, const int* in_sizes, int n_in,
                              void* d_out, int out_size, void* d_ws, size_t ws_size,
                              hipStream_t stream) {
    const float* qp   = (const float*)d_in[0];  // query_points [N,3] f32
    const float* feat = (const float*)d_in[1];  // features [L,T,F] f32
    const int*   fidx = (const int*)d_in[2];    // feature_indexs [L,B] int
    float*       out  = (float*)d_out;          // [N,F] f32

    dim3 grid(NPTS / 256), block(256);
    hipLaunchKernelGGL(nhv_kernel, grid, block, 0, stream, qp, feat, fidx, out);
}